// Round 9
// baseline (243.192 us; speedup 1.0000x reference)
//
#include <hip/hip_runtime.h>
#include <cstdint>
#include <math.h>

#define TT 2048
#define DD 2048
#define NH 16
#define NKV 4
#define HD 128
#define SCALE_F 0.08838834764831845f
#define LOG2E 1.4426950408889634f

#if __has_builtin(__builtin_amdgcn_exp2f)
#define EXP2(x) __builtin_amdgcn_exp2f(x)
#else
#define EXP2(x) exp2f(x)
#endif

typedef int   i32x4 __attribute__((ext_vector_type(4)));
typedef float f32x4 __attribute__((ext_vector_type(4)));
typedef short s16x8 __attribute__((ext_vector_type(8)));

__device__ __forceinline__ i32x4 mfma_i8(i32x4 a, i32x4 b, i32x4 c) {
  return __builtin_amdgcn_mfma_i32_16x16x64_i8(a, b, c, 0, 0, 0);
}
__device__ __forceinline__ f32x4 mfma_bf16(s16x8 a, s16x8 b, f32x4 c) {
  return __builtin_amdgcn_mfma_f32_16x16x32_bf16(a, b, c, 0, 0, 0);
}
__device__ __forceinline__ uint32_t fbits(float f) {
  union { float f; uint32_t u; } x; x.f = f; return x.u;
}
__device__ __forceinline__ ushort bf16_rne(float v) {
  uint32_t u = fbits(v);
  return (ushort)((u + 0x7fffu + ((u >> 16) & 1u)) >> 16);
}
__device__ __forceinline__ float bf16_to_f(ushort h) {
  union { uint32_t u; float f; } x; x.u = ((uint32_t)h) << 16; return x.f;
}

// ---------------------------------------------------------------------------
// Kernel 1: rowwise symmetric int8 quantization for x, wq, wk, wv.
// ---------------------------------------------------------------------------
__global__ __launch_bounds__(256)
void quant_rows_kernel(const float* __restrict__ x, const float* __restrict__ wq,
                       const float* __restrict__ wk, const float* __restrict__ wv,
                       int8_t* __restrict__ qx, float* __restrict__ xs,
                       int8_t* __restrict__ qwq, float* __restrict__ wqs,
                       int8_t* __restrict__ qwk, float* __restrict__ wks,
                       int8_t* __restrict__ qwv, float* __restrict__ wvs) {
  int r = blockIdx.x;
  const float* src; int8_t* dst; float* sc; int row;
  if (r < 2048)      { src = x;  dst = qx;  sc = xs;  row = r; }
  else if (r < 4096) { src = wq; dst = qwq; sc = wqs; row = r - 2048; }
  else if (r < 4608) { src = wk; dst = qwk; sc = wks; row = r - 4096; }
  else               { src = wv; dst = qwv; sc = wvs; row = r - 4608; }
  src += (size_t)row * DD; dst += (size_t)row * DD;
  int tid = threadIdx.x;
  float4 v0 = ((const float4*)src)[2*tid];
  float4 v1 = ((const float4*)src)[2*tid+1];
  float m = fmaxf(fmaxf(fmaxf(fabsf(v0.x), fabsf(v0.y)), fmaxf(fabsf(v0.z), fabsf(v0.w))),
                  fmaxf(fmaxf(fabsf(v1.x), fabsf(v1.y)), fmaxf(fabsf(v1.z), fabsf(v1.w))));
  #pragma unroll
  for (int off = 1; off < 64; off <<= 1) m = fmaxf(m, __shfl_xor(m, off));
  __shared__ float wmax[4];
  if ((tid & 63) == 0) wmax[tid >> 6] = m;
  __syncthreads();
  m = fmaxf(fmaxf(wmax[0], wmax[1]), fmaxf(wmax[2], wmax[3]));
  float s = fmaxf(m / 127.0f, 1e-8f);
  if (tid == 0) sc[row] = s;
  float vv[8] = {v0.x, v0.y, v0.z, v0.w, v1.x, v1.y, v1.z, v1.w};
  uint32_t p0 = 0, p1 = 0;
  #pragma unroll
  for (int i = 0; i < 4; ++i) {
    int q = (int)fminf(fmaxf(rintf(vv[i] / s), -127.0f), 127.0f);
    p0 |= ((uint32_t)q & 0xffu) << (8*i);
  }
  #pragma unroll
  for (int i = 0; i < 4; ++i) {
    int q = (int)fminf(fmaxf(rintf(vv[4+i] / s), -127.0f), 127.0f);
    p1 |= ((uint32_t)q & 0xffu) << (8*i);
  }
  ((uint2*)dst)[tid] = make_uint2(p0, p1);
}

// ---------------------------------------------------------------------------
// Kernel 2: i8-MFMA projection GEMM + dequant + RoPE + rowwise requant.
// Round 9 (= round 8 resubmit + alignment fix): LDS-FREE main loop. MFMA
// fragments (row lg, 16B at lh*16) load directly from global; no barriers or
// ds ops in the K-loop -> compiler pipelines loads with counted vmcnt.
// 2 waves/block, wave w owns 64t x 64o (o-cols w*16 + tj*32 + lg, RoPE pairs
// (d,d+64) lane-local at tj<->tj+2). LDS + 2 barriers in epilogue only.
// Qout row stride 144 (16B-aligned for b128 reads). XCD mapping kept.
// ---------------------------------------------------------------------------
__global__ __launch_bounds__(128)
void proj_kernel(const int8_t* __restrict__ qx, const float* __restrict__ xs,
                 const int8_t* __restrict__ qwq, const float* __restrict__ wqs,
                 const int8_t* __restrict__ qwk, const float* __restrict__ wks,
                 const int8_t* __restrict__ qwv, const float* __restrict__ wvs,
                 int8_t* __restrict__ qq, float* __restrict__ qsc_out,
                 int8_t* __restrict__ kq, float* __restrict__ ksc_out,
                 int8_t* __restrict__ vq, float* __restrict__ vsc_out) {
  // --- XCD-aware bijective decode: id -> (gh, tb) ---
  int id  = blockIdx.x;          // 0..767
  int xcd = id & 7;
  int j   = id >> 3;             // 0..95
  int hg  = xcd >> 1;
  int th  = xcd & 1;
  int gh  = hg*6 + (j % 6);      // 0..23
  int tb  = th*16 + (j / 6);     // 0..31
  int t0  = tb * 64;

  const int8_t* wgt; const float* wsc; int8_t* outq; float* outs; bool doRope;
  if (gh < NH) {
    wgt = qwq + (size_t)gh*HD*DD; wsc = wqs + gh*HD;
    outq = qq + (size_t)gh*TT*HD; outs = qsc_out + (size_t)gh*TT; doRope = true;
  } else if (gh < NH + NKV) {
    int hh = gh - NH;
    wgt = qwk + (size_t)hh*HD*DD; wsc = wks + hh*HD;
    outq = kq + (size_t)hh*TT*HD; outs = ksc_out + (size_t)hh*TT; doRope = true;
  } else {
    int hh = gh - NH - NKV;
    wgt = qwv + (size_t)hh*HD*DD; wsc = wvs + hh*HD;
    outq = vq + (size_t)hh*TT*HD; outs = vsc_out + (size_t)hh*TT; doRope = false;
  }

  int tid = threadIdx.x;
  int w  = tid >> 6;    // wave: o-col group
  int l  = tid & 63;
  int lg = l & 15;
  int lh = l >> 4;

  const int8_t* aBase = qx  + (size_t)(t0 + lg)*DD + lh*16;          // + ti*16*DD
  const int8_t* bBase = wgt + (size_t)(w*16 + lg)*DD + lh*16;        // + tj*32*DD

  i32x4 acc[4][4];   // [ti][tj]
  #pragma unroll
  for (int ti = 0; ti < 4; ++ti)
    #pragma unroll
    for (int tj = 0; tj < 4; ++tj) acc[ti][tj] = (i32x4){0,0,0,0};

  for (int kt = 0; kt < DD/128; ++kt) {
    int ko = kt * 128;
    i32x4 aF[4][2], bF[4][2];
    #pragma unroll
    for (int ti = 0; ti < 4; ++ti) {
      aF[ti][0] = *(const i32x4*)(aBase + (size_t)ti*16*DD + ko);
      aF[ti][1] = *(const i32x4*)(aBase + (size_t)ti*16*DD + ko + 64);
    }
    #pragma unroll
    for (int tj = 0; tj < 4; ++tj) {
      bF[tj][0] = *(const i32x4*)(bBase + (size_t)tj*32*DD + ko);
      bF[tj][1] = *(const i32x4*)(bBase + (size_t)tj*32*DD + ko + 64);
    }
    #pragma unroll
    for (int s = 0; s < 2; ++s)
      #pragma unroll
      for (int tj = 0; tj < 4; ++tj)
        #pragma unroll
        for (int ti = 0; ti < 4; ++ti)
          acc[ti][tj] = mfma_i8(aF[ti][s], bF[tj][s], acc[ti][tj]);
  }

  // ---- epilogue: dequant -> RoPE -> rowwise requant ----
  __shared__ float  smax[2][64];
  __shared__ int8_t Qout[64 * 144];

  float y[4][4][4];   // [ti][tj][rr]; o-col(tj) = w*16 + tj*32 + lg
  #pragma unroll
  for (int ti = 0; ti < 4; ++ti)
    #pragma unroll
    for (int rr = 0; rr < 4; ++rr) {
      float xsi = xs[t0 + ti*16 + lh*4 + rr];
      #pragma unroll
      for (int tj = 0; tj < 4; ++tj)
        y[ti][tj][rr] = (float)acc[ti][tj][rr] * xsi * wsc[w*16 + tj*32 + lg];
    }

  if (doRope) {
    float invf[2];
    #pragma unroll
    for (int tj = 0; tj < 2; ++tj)
      invf[tj] = 1.0f / powf(1000000.0f, (float)(w*16 + tj*32 + lg) * (1.0f/64.0f));
    #pragma unroll
    for (int ti = 0; ti < 4; ++ti)
      #pragma unroll
      for (int rr = 0; rr < 4; ++rr) {
        float trow = (float)(t0 + ti*16 + lh*4 + rr);
        #pragma unroll
        for (int tj = 0; tj < 2; ++tj) {
          float sn, cs;
          sincosf(trow * invf[tj], &sn, &cs);
          float lo = y[ti][tj][rr], hi = y[ti][tj+2][rr];
          y[ti][tj][rr]   = lo*cs - hi*sn;     // d < 64
          y[ti][tj+2][rr] = hi*cs + lo*sn;     // d >= 64
        }
      }
  }

  // per-row max over this wave's 64 cols, then cross-wave via LDS
  #pragma unroll
  for (int ti = 0; ti < 4; ++ti)
    #pragma unroll
    for (int rr = 0; rr < 4; ++rr) {
      int row = ti*16 + lh*4 + rr;
      float mx = fabsf(y[ti][0][rr]);
      #pragma unroll
      for (int tj = 1; tj < 4; ++tj) mx = fmaxf(mx, fabsf(y[ti][tj][rr]));
      mx = fmaxf(mx, __shfl_xor(mx, 1));
      mx = fmaxf(mx, __shfl_xor(mx, 2));
      mx = fmaxf(mx, __shfl_xor(mx, 4));
      mx = fmaxf(mx, __shfl_xor(mx, 8));
      if (lg == 0) smax[w][row] = mx;
    }
  __syncthreads();
  #pragma unroll
  for (int ti = 0; ti < 4; ++ti)
    #pragma unroll
    for (int rr = 0; rr < 4; ++rr) {
      int row = ti*16 + lh*4 + rr;
      float mx = fmaxf(smax[0][row], smax[1][row]);
      float s = fmaxf(mx / 127.0f, 1e-8f);
      if (w == 0 && lg == 0) outs[t0 + row] = s;
      float rinv = 1.0f / s;
      #pragma unroll
      for (int tj = 0; tj < 4; ++tj) {
        int qv = (int)fminf(fmaxf(rintf(y[ti][tj][rr] * rinv), -127.0f), 127.0f);
        Qout[row*144 + w*16 + tj*32 + lg] = (int8_t)qv;
      }
    }
  __syncthreads();
  #pragma unroll
  for (int i = 0; i < 4; ++i) {
    int idx = tid + i*128, r = idx >> 3, c = idx & 7;
    *(i32x4*)&outq[(size_t)(t0 + r)*HD + c*16] = *(const i32x4*)&Qout[r*144 + c*16];
  }
}

// ---------------------------------------------------------------------------
// Kernel 3: MFMA flash attention, operand-swapped, K-split, reg-prefetch.
// (unchanged from round 5 — verified)
// ---------------------------------------------------------------------------
__global__ __launch_bounds__(256)
void attn_mfma_kernel(const int8_t* __restrict__ qq, const float* __restrict__ qsc_in,
                      const int8_t* __restrict__ kq, const float* __restrict__ ksc_in,
                      const int8_t* __restrict__ vq, const float* __restrict__ vsc_in,
                      ushort* __restrict__ aoh, ushort* __restrict__ aol,
                      float* __restrict__ opart0, float* __restrict__ opart1,
                      float* __restrict__ mlm, float* __restrict__ mll) {
  int id = blockIdx.x;
  int h, qb, sp, ktb, kte;
  if (id < 512) {
    sp = id & 1;
    int r = id >> 1;
    h  = r & 15;
    qb = 31 - (r >> 4);
    int nkt = qb + 1, mid = nkt >> 1;
    ktb = sp ? mid : 0;
    kte = sp ? nkt : mid;
  } else {
    int r = id - 512;
    h  = r & 15;
    qb = 15 - (r >> 4);
    sp = -1;
    ktb = 0; kte = qb + 1;
  }
  int hk  = h >> 2;
  int qb0 = qb * 64;
  int nkt_full = qb + 1;

  __shared__ int8_t Ks[64 * 144];
  __shared__ ushort Vt[128 * 72];
  __shared__ float  Pf[4][16 * 68];

  int tid = threadIdx.x;
  int w  = tid >> 6;
  int l  = tid & 63;
  int lg = l & 15;
  int lh = l >> 4;

  const int8_t* qp = &qq[((size_t)h*TT + qb0 + 16*w + lg)*HD + lh*16];
  i32x4 qa0 = *(const i32x4*)qp;
  i32x4 qa1 = *(const i32x4*)(qp + 64);

  int myq = qb0 + 16*w + lg;
  float qsl = qsc_in[(size_t)h*TT + myq] * (SCALE_F * LOG2E);

  float mrun = -1e30f, lrun = 0.f;
  f32x4 acc_o[8];
  #pragma unroll
  for (int dt = 0; dt < 8; ++dt) acc_o[dt] = (f32x4){0.f, 0.f, 0.f, 0.f};

  i32x4 kreg[2];
  int2  vreg[2][2];

#define ISSUE_LOADS(KT)                                                         \
  {                                                                             \
    int kk0 = (KT) * 64;                                                        \
    _Pragma("unroll")                                                           \
    for (int i = 0; i < 2; ++i) {                                               \
      int a = tid + i*256, r = a >> 3, c = a & 7;                               \
      kreg[i] = *(const i32x4*)&kq[((size_t)hk*TT + kk0 + r)*HD + c*16];        \
    }                                                                           \
    _Pragma("unroll")                                                           \
    for (int it = 0; it < 2; ++it) {                                            \
      int a2 = tid + it*256, m2 = a2 & 31, d0 = (a2 >> 5) * 8;                  \
      vreg[it][0] = *(const int2*)&vq[((size_t)hk*TT + kk0 + 2*m2    )*HD + d0];\
      vreg[it][1] = *(const int2*)&vq[((size_t)hk*TT + kk0 + 2*m2 + 1)*HD + d0];\
    }                                                                           \
  }

  ISSUE_LOADS(ktb);

  for (int kt = ktb; kt < kte; ++kt) {
    int k0 = kt * 64;
    __syncthreads();
    #pragma unroll
    for (int i = 0; i < 2; ++i) {
      int a = tid + i*256, r = a >> 3, c = a & 7;
      *(i32x4*)&Ks[r*144 + c*16] = kreg[i];
    }
    #pragma unroll
    for (int it = 0; it < 2; ++it) {
      int a2 = tid + it*256, m2 = a2 & 31, d0 = (a2 >> 5) * 8;
      int xa = vreg[it][0].x, ya = vreg[it][0].y;
      int xb = vreg[it][1].x, yb = vreg[it][1].y;
      #pragma unroll
      for (int j = 0; j < 4; ++j) {
        int v0 = (xa << (24 - 8*j)) >> 24;
        int v1 = (xb << (24 - 8*j)) >> 24;
        uint32_t pk = (fbits((float)v0) >> 16) | ((fbits((float)v1) >> 16) << 16);
        *(uint32_t*)&Vt[(d0 + j)*72 + 2*m2] = pk;
      }
      #pragma unroll
      for (int j = 0; j < 4; ++j) {
        int v0 = (ya << (24 - 8*j)) >> 24;
        int v1 = (yb << (24 - 8*j)) >> 24;
        uint32_t pk = (fbits((float)v0) >> 16) | ((fbits((float)v1) >> 16) << 16);
        *(uint32_t*)&Vt[(d0 + 4 + j)*72 + 2*m2] = pk;
      }
    }
    __syncthreads();
    if (kt + 1 < kte) ISSUE_LOADS(kt + 1);

    i32x4 sacc[4];
    #pragma unroll
    for (int t = 0; t < 4; ++t) sacc[t] = (i32x4){0, 0, 0, 0};
    #pragma unroll
    for (int t = 0; t < 4; ++t) {
      const int8_t* kp = &Ks[(16*t + lg)*144 + lh*16];
      i32x4 b0 = *(const i32x4*)kp;
      i32x4 b1 = *(const i32x4*)(kp + 64);
      sacc[t] = mfma_i8(b0, qa0, sacc[t]);
      sacc[t] = mfma_i8(b1, qa1, sacc[t]);
    }

    f32x4 ksv4[4], vsv4[4];
    #pragma unroll
    for (int t = 0; t < 4; ++t) {
      ksv4[t] = *(const f32x4*)&ksc_in[(size_t)hk*TT + k0 + 16*t + 4*lh];
      vsv4[t] = *(const f32x4*)&vsc_in[(size_t)hk*TT + k0 + 16*t + 4*lh];
    }

    bool maskTile = (kt == nkt_full - 1);
    float sf[4][4];
    #pragma unroll
    for (int t = 0; t < 4; ++t)
      #pragma unroll
      for (int rr = 0; rr < 4; ++rr) {
        float v = (float)sacc[t][rr] * qsl * ksv4[t][rr];
        if (maskTile) {
          int kkg = k0 + 16*t + 4*lh + rr;
          v = (kkg <= myq) ? v : -1e30f;
        }
        sf[t][rr] = v;
      }

    float rm = sf[0][0];
    #pragma unroll
    for (int t = 0; t < 4; ++t)
      #pragma unroll
      for (int rr = 0; rr < 4; ++rr) rm = fmaxf(rm, sf[t][rr]);
    rm = fmaxf(rm, __shfl_xor(rm, 16));
    rm = fmaxf(rm, __shfl_xor(rm, 32));
    float mnew = fmaxf(mrun, rm);
    float corr = EXP2(mrun - mnew);
    mrun = mnew;
    float p[4][4];
    float ps = 0.f;
    #pragma unroll
    for (int t = 0; t < 4; ++t)
      #pragma unroll
      for (int rr = 0; rr < 4; ++rr) { p[t][rr] = EXP2(sf[t][rr] - mnew); ps += p[t][rr]; }
    ps += __shfl_xor(ps, 16);
    ps += __shfl_xor(ps, 32);
    lrun = lrun * corr + ps;

    #pragma unroll
    for (int t = 0; t < 4; ++t) {
      f32x4 pw;
      #pragma unroll
      for (int rr = 0; rr < 4; ++rr) pw[rr] = p[t][rr] * vsv4[t][rr];
      *(f32x4*)&Pf[w][lg*68 + 16*t + 4*lh] = pw;
    }

    #pragma unroll
    for (int dt = 0; dt < 8; ++dt)
      #pragma unroll
      for (int rr = 0; rr < 4; ++rr) acc_o[dt][rr] *= corr;

    s16x8 pahi[2], palo[2];
    #pragma unroll
    for (int kb = 0; kb < 2; ++kb) {
      const float* pr = &Pf[w][lg*68 + kb*32 + lh*8];
      f32x4 x0 = *(const f32x4*)pr;
      f32x4 x1 = *(const f32x4*)(pr + 4);
      float xv[8] = {x0.x, x0.y, x0.z, x0.w, x1.x, x1.y, x1.z, x1.w};
      float lv[8];
      #pragma unroll
      for (int j = 0; j < 8; ++j) {
        uint32_t hb = fbits(xv[j]) & 0xffff0000u;
        union { uint32_t u; float f; } hf; hf.u = hb;
        lv[j] = xv[j] - hf.f;
      }
      union { uint32_t u[4]; s16x8 v; } H, L;
      #pragma unroll
      for (int jj = 0; jj < 4; ++jj) {
        H.u[jj] = (fbits(xv[2*jj]) >> 16) | (fbits(xv[2*jj+1]) & 0xffff0000u);
        L.u[jj] = (fbits(lv[2*jj]) >> 16) | (fbits(lv[2*jj+1]) & 0xffff0000u);
      }
      pahi[kb] = H.v; palo[kb] = L.v;
    }

    #pragma unroll
    for (int dt = 0; dt < 8; ++dt) {
      #pragma unroll
      for (int kb = 0; kb < 2; ++kb) {
        s16x8 vb = *(const s16x8*)&Vt[(16*dt + lg)*72 + kb*32 + lh*8];
        acc_o[dt] = mfma_bf16(vb, pahi[kb], acc_o[dt]);
        acc_o[dt] = mfma_bf16(vb, palo[kb], acc_o[dt]);
      }
    }
  }
#undef ISSUE_LOADS

  if (sp < 0) {
    float invv = 1.0f / lrun;
    size_t base = (size_t)myq*DD + (size_t)h*HD;
    #pragma unroll
    for (int dt = 0; dt < 8; ++dt) {
      ushort4 Hv, Lv;
      float v0 = acc_o[dt][0]*invv, v1 = acc_o[dt][1]*invv;
      float v2 = acc_o[dt][2]*invv, v3 = acc_o[dt][3]*invv;
      Hv.x = bf16_rne(v0); Hv.y = bf16_rne(v1); Hv.z = bf16_rne(v2); Hv.w = bf16_rne(v3);
      Lv.x = bf16_rne(v0 - bf16_to_f(Hv.x)); Lv.y = bf16_rne(v1 - bf16_to_f(Hv.y));
      Lv.z = bf16_rne(v2 - bf16_to_f(Hv.z)); Lv.w = bf16_rne(v3 - bf16_to_f(Hv.w));
      *(ushort4*)&aoh[base + 16*dt + 4*lh] = Hv;
      *(ushort4*)&aol[base + 16*dt + 4*lh] = Lv;
    }
  } else {
    int tile = h*16 + (qb - 16);
    float* op = (sp == 0 ? opart0 : opart1) + (size_t)tile*8192 + (size_t)(16*w + lg)*128;
    #pragma unroll
    for (int dt = 0; dt < 8; ++dt)
      *(f32x4*)&op[16*dt + 4*lh] = acc_o[dt];
    if (lh == 0) {
      mlm[sp*16384 + tile*64 + 16*w + lg] = mrun;
      mll[sp*16384 + tile*64 + 16*w + lg] = lrun;
    }
  }
}

// ---------------------------------------------------------------------------
// Kernel 3b: merge the two K-split halves for qb >= 16.
// ---------------------------------------------------------------------------
__global__ __launch_bounds__(256)
void merge_kernel(const float* __restrict__ opart0, const float* __restrict__ opart1,
                  const float* __restrict__ mlm, const float* __restrict__ mll,
                  ushort* __restrict__ aoh, ushort* __restrict__ aol) {
  int tile = blockIdx.x;
  int h = tile >> 4, j = tile & 15;
  int tid = threadIdx.x;
  int row = tid >> 2;
  int cseg = (tid & 3) * 32;
  float m1 = mlm[tile*64 + row], m2 = mlm[16384 + tile*64 + row];
  float l1 = mll[tile*64 + row], l2 = mll[16384 + tile*64 + row];
  float m = fmaxf(m1, m2);
  float c1 = EXP2(m1 - m), c2 = EXP2(m2 - m);
  float inv = 1.0f / (l1*c1 + l2*c2);
  const float* p0 = opart0 + (size_t)tile*8192 + row*128 + cseg;
  const float* p1 = opart1 + (size_t)tile*8192 + row*128 + cseg;
  size_t ob = (size_t)(1024 + j*64 + row)*DD + (size_t)h*HD + cseg;
  #pragma unroll
  for (int c4 = 0; c4 < 8; ++c4) {
    f32x4 a = *(const f32x4*)&p0[c4*4];
    f32x4 b = *(const f32x4*)&p1[c4*4];
    ushort4 Hv, Lv;
    #pragma unroll
    for (int e = 0; e < 4; ++e) {
      float v = (a[e]*c1 + b[e]*c2) * inv;
      ushort hb = bf16_rne(v);
      ushort lb = bf16_rne(v - bf16_to_f(hb));
      ((ushort*)&Hv)[e] = hb;
      ((ushort*)&Lv)[e] = lb;
    }
    *(ushort4*)&aoh[ob + c4*4] = Hv;
    *(ushort4*)&aol[ob + c4*4] = Lv;
  }
}

// ---------------------------------------------------------------------------
// Kernel 3c: split wo (f32) into hi/lo bf16.
// ---------------------------------------------------------------------------
__global__ __launch_bounds__(256)
void wcvt_kernel(const float* __restrict__ wom, ushort* __restrict__ woh,
                 ushort* __restrict__ wol) {
  size_t base = ((size_t)blockIdx.x * 256 + threadIdx.x) * 8;
  float4 a = *(const float4*)&wom[base];
  float4 b = *(const float4*)&wom[base + 4];
  float vv[8] = {a.x, a.y, a.z, a.w, b.x, b.y, b.z, b.w};
  s16x8 H, L;
  #pragma unroll
  for (int j = 0; j < 8; ++j) {
    ushort hb = bf16_rne(vv[j]);
    float lo = vv[j] - bf16_to_f(hb);
    H[j] = (short)hb;
    L[j] = (short)bf16_rne(lo);
  }
  *(s16x8*)&woh[base] = H;
  *(s16x8*)&wol[base] = L;
}

// ---------------------------------------------------------------------------
// Kernel 4: wo GEMM on bf16 MFMA with 3-product split (unchanged, verified).
// ---------------------------------------------------------------------------
__global__ __launch_bounds__(256)
void wo_gemm_kernel(const ushort* __restrict__ aoh, const ushort* __restrict__ aol,
                    const ushort* __restrict__ woh, const ushort* __restrict__ wol,
                    float* __restrict__ outp) {
  int o0 = blockIdx.x * 128;
  int t0 = blockIdx.y * 128;
  __shared__ ushort AH[128 * 72];
  __shared__ ushort AL[128 * 72];
  __shared__ ushort BH[128 * 72];
  __shared__ ushort BL[128 * 72];
  int tid = threadIdx.x;
  int wv4 = tid >> 6;
  int wr = wv4 >> 1, wc = wv4 & 1;
  int l  = tid & 63;
  int lg = l & 15;
  int lh = l >> 4;

  f32x4 acc[4][4];
  #pragma unroll
  for (int ti = 0; ti < 4; ++ti)
    #pragma unroll
    for (int tj = 0; tj < 4; ++tj) acc[ti][tj] = (f32x4){0.f,0.f,0.f,0.f};

  for (int kt = 0; kt < DD/64; ++kt) {
    int k0 = kt * 64;
    __syncthreads();
    #pragma unroll
    for (int i = 0; i < 4; ++i) {
      int idx = tid + i*256, r = idx >> 3, c = idx & 7;
      size_t ga = (size_t)(t0 + r)*DD + k0 + c*8;
      size_t gb = (size_t)(o0 + r)*DD + k0 + c*8;
      *(s16x8*)&AH[r*72 + c*8] = *(const s16x8*)&aoh[ga];
      *(s16x8*)&AL[r*72 + c*8] = *(const s16x8*)&aol[ga];
      *(s16x8*)&BH[r*72 + c*8] = *(const s16x8*)&woh[gb];
      *(s16x8*)&BL[r*72 + c*8] = *(const s16x8*)&wol[gb];
    }
    __syncthreads();
    #pragma unroll
    for (int s = 0; s < 2; ++s) {
      s16x8 ah[4], al[4];
      #pragma unroll
      for (int ti = 0; ti < 4; ++ti) {
        int ab = (wr*64 + ti*16 + lg)*72 + s*32 + lh*8;
        ah[ti] = *(const s16x8*)&AH[ab];
        al[ti] = *(const s16x8*)&AL[ab];
      }
      #pragma unroll
      for (int tj = 0; tj < 4; ++tj) {
        int bb = (wc*64 + tj*16 + lg)*72 + s*32 + lh*8;
        s16x8 bh = *(const s16x8*)&BH[bb];
        s16x8 bl = *(const s16x8*)&BL[bb];
        #pragma unroll
        for (int ti = 0; ti < 4; ++ti) {
          acc[ti][tj] = mfma_bf16(ah[ti], bh, acc[ti][tj]);
          acc[ti][tj] = mfma_bf16(ah[ti], bl, acc[ti][tj]);
          acc[ti][tj] = mfma_bf16(al[ti], bh, acc[ti][tj]);
        }
      }
    }
  }

  #pragma unroll
  for (int ti = 0; ti < 4; ++ti)
    #pragma unroll
    for (int tj = 0; tj < 4; ++tj)
      #pragma unroll
      for (int rr = 0; rr < 4; ++rr) {
        int t = t0 + wr*64 + ti*16 + lh*4 + rr;
        int o = o0 + wc*64 + tj*16 + lg;
        outp[(size_t)t*DD + o] = acc[ti][tj][rr];
      }
}

// ---------------------------------------------------------------------------
extern "C" void kernel_launch(void* const* d_in, const int* in_sizes, int n_in,
                              void* d_out, int out_size, void* d_ws, size_t ws_size,
                              hipStream_t stream) {
  (void)in_sizes; (void)n_in; (void)out_size; (void)ws_size;
  const float* x  = (const float*)d_in[0];
  const float* wq = (const float*)d_in[1];
  const float* wk = (const float*)d_in[2];
  const float* wv = (const float*)d_in[3];
  const float* wo = (const float*)d_in[4];
  float* out = (float*)d_out;

  char* ws = (char*)d_ws;
  const size_t MB = 1048576;
  int8_t* qx  = (int8_t*)(ws);           // [2048][2048]; dead after proj
  int8_t* qwq = (int8_t*)(ws + 4*MB);    // dead after proj
  int8_t* qwk = (int8_t*)(ws + 8*MB);    // dead after proj
  int8_t* qwv = (int8_t*)(ws + 9*MB);    // dead after proj
  int8_t* qqp = (int8_t*)(ws + 10*MB);   // [16][2048][128]; dead after attn
  int8_t* kqp = (int8_t*)(ws + 14*MB);   // [4][2048][128];  dead after attn
  int8_t* vqp = (int8_t*)(ws + 15*MB);   // [4][2048][128];  dead after attn
  float* xs  = (float*)(ws + 16*MB);
  float* wqs = xs + 2048;
  float* wks = wqs + 2048;
  float* wvs = wks + 512;
  float* qsc = wvs + 512;
  float* ksc = qsc + (size_t)NH*TT;
  float* vsc = ksc + (size_t)NKV*TT;
  ushort* aoh = (ushort*)(ws + 16*MB + 262144);   // 8 MB
  ushort* aol = (ushort*)(ws + 24*MB + 262144);   // 8 MB (ends 32.25 MB)
  // attn-phase scratch over dead regions:
  float* opart0 = (float*)(ws);                   // 8 MiB (over qx/qwq, dead)
  float* mlm    = (float*)(ws + 8*MB);            // 128 KB (over qwk, dead)
  float* mll    = (float*)(ws + 8*MB + 131072);   // 128 KB
  float* opart1 = out;                            // 8 MiB scratch in d_out
  // wo-phase scratch (after merge, everything below 16 MB is dead):
  ushort* woh = (ushort*)(ws);                    // 8 MB
  ushort* wol = (ushort*)(ws + 8*MB);             // 8 MB

  quant_rows_kernel<<<5120, 256, 0, stream>>>(x, wq, wk, wv,
                                              qx, xs, qwq, wqs, qwk, wks, qwv, wvs);
  proj_kernel<<<768, 128, 0, stream>>>(
      qx, xs, qwq, wqs, qwk, wks, qwv, wvs,
      qqp, qsc, kqp, ksc, vqp, vsc);
  attn_mfma_kernel<<<768, 256, 0, stream>>>(
      qqp, qsc, kqp, ksc, vqp, vsc, aoh, aol, opart0, opart1, mlm, mll);
  merge_kernel<<<256, 256, 0, stream>>>(opart0, opart1, mlm, mll, aoh, aol);
  wcvt_kernel<<<2048, 256, 0, stream>>>(wo, woh, wol);
  wo_gemm_kernel<<<dim3(DD/128, TT/128), 256, 0, stream>>>(aoh, aol, woh, wol, out);
}

// Round 11
// 200.023 us; speedup vs baseline: 1.2158x; 1.2158x over previous
//
#include <hip/hip_runtime.h>
#include <cstdint>
#include <math.h>

#define TT 2048
#define DD 2048
#define NH 16
#define NKV 4
#define HD 128
#define SCALE_F 0.08838834764831845f
#define LOG2E 1.4426950408889634f

#if __has_builtin(__builtin_amdgcn_exp2f)
#define EXP2(x) __builtin_amdgcn_exp2f(x)
#else
#define EXP2(x) exp2f(x)
#endif

typedef int   i32x4 __attribute__((ext_vector_type(4)));
typedef float f32x4 __attribute__((ext_vector_type(4)));
typedef short s16x8 __attribute__((ext_vector_type(8)));

__device__ __forceinline__ i32x4 mfma_i8(i32x4 a, i32x4 b, i32x4 c) {
  return __builtin_amdgcn_mfma_i32_16x16x64_i8(a, b, c, 0, 0, 0);
}
__device__ __forceinline__ f32x4 mfma_bf16(s16x8 a, s16x8 b, f32x4 c) {
  return __builtin_amdgcn_mfma_f32_16x16x32_bf16(a, b, c, 0, 0, 0);
}
__device__ __forceinline__ uint32_t fbits(float f) {
  union { float f; uint32_t u; } x; x.f = f; return x.u;
}
__device__ __forceinline__ ushort bf16_rne(float v) {
  uint32_t u = fbits(v);
  return (ushort)((u + 0x7fffu + ((u >> 16) & 1u)) >> 16);
}
__device__ __forceinline__ float bf16_to_f(ushort h) {
  union { uint32_t u; float f; } x; x.u = ((uint32_t)h) << 16; return x.f;
}

// ---------------------------------------------------------------------------
// Kernel 0: RoPE cos/sin table — tab[t*64+d] = (cos(t*invf(d)), sin(t*invf(d))).
// Same per-(t,d) arithmetic the fused epilogue used -> bit-identical values.
// 131072 entries; replaces 3.1M inline sincosf in proj with 8B table loads.
// ---------------------------------------------------------------------------
__global__ __launch_bounds__(256)
void rope_table_kernel(float2* __restrict__ tab) {
  int idx = blockIdx.x * 256 + threadIdx.x;   // 0..131071
  int t = idx >> 6, d = idx & 63;
  float inv = 1.0f / powf(1000000.0f, (float)d * (1.0f/64.0f));
  float ang = (float)t * inv;
  float sn, cs;
  sincosf(ang, &sn, &cs);
  tab[idx] = make_float2(cs, sn);
}

// ---------------------------------------------------------------------------
// Kernel 1: rowwise symmetric int8 quantization for x, wq, wk, wv.
// ---------------------------------------------------------------------------
__global__ __launch_bounds__(256)
void quant_rows_kernel(const float* __restrict__ x, const float* __restrict__ wq,
                       const float* __restrict__ wk, const float* __restrict__ wv,
                       int8_t* __restrict__ qx, float* __restrict__ xs,
                       int8_t* __restrict__ qwq, float* __restrict__ wqs,
                       int8_t* __restrict__ qwk, float* __restrict__ wks,
                       int8_t* __restrict__ qwv, float* __restrict__ wvs) {
  int r = blockIdx.x;
  const float* src; int8_t* dst; float* sc; int row;
  if (r < 2048)      { src = x;  dst = qx;  sc = xs;  row = r; }
  else if (r < 4096) { src = wq; dst = qwq; sc = wqs; row = r - 2048; }
  else if (r < 4608) { src = wk; dst = qwk; sc = wks; row = r - 4096; }
  else               { src = wv; dst = qwv; sc = wvs; row = r - 4608; }
  src += (size_t)row * DD; dst += (size_t)row * DD;
  int tid = threadIdx.x;
  float4 v0 = ((const float4*)src)[2*tid];
  float4 v1 = ((const float4*)src)[2*tid+1];
  float m = fmaxf(fmaxf(fmaxf(fabsf(v0.x), fabsf(v0.y)), fmaxf(fabsf(v0.z), fabsf(v0.w))),
                  fmaxf(fmaxf(fabsf(v1.x), fabsf(v1.y)), fmaxf(fabsf(v1.z), fabsf(v1.w))));
  #pragma unroll
  for (int off = 1; off < 64; off <<= 1) m = fmaxf(m, __shfl_xor(m, off));
  __shared__ float wmax[4];
  if ((tid & 63) == 0) wmax[tid >> 6] = m;
  __syncthreads();
  m = fmaxf(fmaxf(wmax[0], wmax[1]), fmaxf(wmax[2], wmax[3]));
  float s = fmaxf(m / 127.0f, 1e-8f);
  if (tid == 0) sc[row] = s;
  float vv[8] = {v0.x, v0.y, v0.z, v0.w, v1.x, v1.y, v1.z, v1.w};
  uint32_t p0 = 0, p1 = 0;
  #pragma unroll
  for (int i = 0; i < 4; ++i) {
    int q = (int)fminf(fmaxf(rintf(vv[i] / s), -127.0f), 127.0f);
    p0 |= ((uint32_t)q & 0xffu) << (8*i);
  }
  #pragma unroll
  for (int i = 0; i < 4; ++i) {
    int q = (int)fminf(fmaxf(rintf(vv[4+i] / s), -127.0f), 127.0f);
    p1 |= ((uint32_t)q & 0xffu) << (8*i);
  }
  ((uint2*)dst)[tid] = make_uint2(p0, p1);
}

// ---------------------------------------------------------------------------
// Kernel 2: i8-MFMA projection GEMM + dequant + RoPE + rowwise requant.
// Round 11 (= round 10 resubmit): base = round-7 variant (best measured:
// LDS staging, reg-prefetch, XCD bijective partition). Single change vs r7:
// RoPE via precomputed table loads (coalesced 8B float2) instead of
// 32 inline sincosf + 2 powf per thread.
// ---------------------------------------------------------------------------
__global__ __launch_bounds__(128)
void proj_kernel(const int8_t* __restrict__ qx, const float* __restrict__ xs,
                 const int8_t* __restrict__ qwq, const float* __restrict__ wqs,
                 const int8_t* __restrict__ qwk, const float* __restrict__ wks,
                 const int8_t* __restrict__ qwv, const float* __restrict__ wvs,
                 const float2* __restrict__ ropet,
                 int8_t* __restrict__ qq, float* __restrict__ qsc_out,
                 int8_t* __restrict__ kq, float* __restrict__ ksc_out,
                 int8_t* __restrict__ vq, float* __restrict__ vsc_out) {
  // --- XCD-aware bijective decode: id -> (gh, tb) ---
  int id  = blockIdx.x;          // 0..767
  int xcd = id & 7;
  int j   = id >> 3;             // 0..95
  int hg  = xcd >> 1;
  int th  = xcd & 1;
  int gh  = hg*6 + (j % 6);      // 0..23
  int tb  = th*16 + (j / 6);     // 0..31
  int t0  = tb * 64;

  const int8_t* wgt; const float* wsc; int8_t* outq; float* outs; bool doRope;
  if (gh < NH) {
    wgt = qwq + (size_t)gh*HD*DD; wsc = wqs + gh*HD;
    outq = qq + (size_t)gh*TT*HD; outs = qsc_out + (size_t)gh*TT; doRope = true;
  } else if (gh < NH + NKV) {
    int hh = gh - NH;
    wgt = qwk + (size_t)hh*HD*DD; wsc = wks + hh*HD;
    outq = kq + (size_t)hh*TT*HD; outs = ksc_out + (size_t)hh*TT; doRope = true;
  } else {
    int hh = gh - NH - NKV;
    wgt = qwv + (size_t)hh*HD*DD; wsc = wvs + hh*HD;
    outq = vq + (size_t)hh*TT*HD; outs = vsc_out + (size_t)hh*TT; doRope = false;
  }

  __shared__ int8_t As[64 * 144];    // [t][k], 144B row stride
  __shared__ int8_t Bs[128 * 144];   // [o][k]
  int tid = threadIdx.x;
  int w  = tid >> 6;    // wave: t rows w*32 .. +31
  int l  = tid & 63;
  int lg = l & 15;
  int lh = l >> 4;

  i32x4 acc[2][8];
  #pragma unroll
  for (int ti = 0; ti < 2; ++ti)
    #pragma unroll
    for (int tj = 0; tj < 8; ++tj) acc[ti][tj] = (i32x4){0,0,0,0};

  i32x4 prefA[4], prefB[8];

#define PROJ_ISSUE(KT)                                                          \
  {                                                                             \
    int kk0 = (KT) * 128;                                                       \
    _Pragma("unroll")                                                           \
    for (int i = 0; i < 4; ++i) {                                               \
      int idx = tid + i*128, r = idx >> 3, c = idx & 7;                         \
      prefA[i] = *(const i32x4*)&qx[(size_t)(t0 + r)*DD + kk0 + c*16];          \
    }                                                                           \
    _Pragma("unroll")                                                           \
    for (int i = 0; i < 8; ++i) {                                               \
      int idx = tid + i*128, r = idx >> 3, c = idx & 7;                         \
      prefB[i] = *(const i32x4*)&wgt[(size_t)r*DD + kk0 + c*16];                \
    }                                                                           \
  }

  PROJ_ISSUE(0);

  for (int kt = 0; kt < DD/128; ++kt) {
    __syncthreads();   // prev compute done with As/Bs
    #pragma unroll
    for (int i = 0; i < 4; ++i) {
      int idx = tid + i*128, r = idx >> 3, c = idx & 7;
      *(i32x4*)&As[r*144 + c*16] = prefA[i];
    }
    #pragma unroll
    for (int i = 0; i < 8; ++i) {
      int idx = tid + i*128, r = idx >> 3, c = idx & 7;
      *(i32x4*)&Bs[r*144 + c*16] = prefB[i];
    }
    __syncthreads();
    if (kt + 1 < DD/128) PROJ_ISSUE(kt + 1);

    #pragma unroll
    for (int s = 0; s < 2; ++s) {
      i32x4 a0 = *(const i32x4*)&As[(w*32 + lg)*144      + s*64 + lh*16];
      i32x4 a1 = *(const i32x4*)&As[(w*32 + 16 + lg)*144 + s*64 + lh*16];
      #pragma unroll
      for (int tj = 0; tj < 8; ++tj) {
        i32x4 b = *(const i32x4*)&Bs[(tj*16 + lg)*144 + s*64 + lh*16];
        acc[0][tj] = mfma_i8(a0, b, acc[0][tj]);
        acc[1][tj] = mfma_i8(a1, b, acc[1][tj]);
      }
    }
  }
#undef PROJ_ISSUE

  // ---- epilogue: dequant -> RoPE (table) -> rowwise requant ----
  float y[2][8][4];
  #pragma unroll
  for (int ti = 0; ti < 2; ++ti)
    #pragma unroll
    for (int rr = 0; rr < 4; ++rr) {
      int tl = w*32 + ti*16 + lh*4 + rr;
      float xsi = xs[t0 + tl];
      #pragma unroll
      for (int tj = 0; tj < 8; ++tj)
        y[ti][tj][rr] = (float)acc[ti][tj][rr] * xsi * wsc[tj*16 + lg];
    }

  if (doRope) {
    #pragma unroll
    for (int ti = 0; ti < 2; ++ti)
      #pragma unroll
      for (int rr = 0; rr < 4; ++rr) {
        int trow = t0 + w*32 + ti*16 + lh*4 + rr;
        const float2* tr = &ropet[trow * 64];
        #pragma unroll
        for (int tj = 0; tj < 4; ++tj) {
          float2 cssn = tr[tj*16 + lg];      // d = tj*16+lg (< 64)
          float lo = y[ti][tj][rr], hi = y[ti][tj+4][rr];
          y[ti][tj][rr]   = lo*cssn.x - hi*cssn.y;
          y[ti][tj+4][rr] = hi*cssn.x + lo*cssn.y;
        }
      }
  }

  __syncthreads();   // all waves done reading As/Bs; reuse As for output tile
  #pragma unroll
  for (int ti = 0; ti < 2; ++ti)
    #pragma unroll
    for (int rr = 0; rr < 4; ++rr) {
      int tl = w*32 + ti*16 + lh*4 + rr;
      float mx = fabsf(y[ti][0][rr]);
      #pragma unroll
      for (int tj = 1; tj < 8; ++tj) mx = fmaxf(mx, fabsf(y[ti][tj][rr]));
      mx = fmaxf(mx, __shfl_xor(mx, 1));
      mx = fmaxf(mx, __shfl_xor(mx, 2));
      mx = fmaxf(mx, __shfl_xor(mx, 4));
      mx = fmaxf(mx, __shfl_xor(mx, 8));
      float s = fmaxf(mx / 127.0f, 1e-8f);
      if (lg == 0) outs[t0 + tl] = s;
      #pragma unroll
      for (int tj = 0; tj < 8; ++tj) {
        int qv = (int)fminf(fmaxf(rintf(y[ti][tj][rr] / s), -127.0f), 127.0f);
        As[tl*144 + tj*16 + lg] = (int8_t)qv;
      }
    }
  __syncthreads();
  #pragma unroll
  for (int i = 0; i < 4; ++i) {
    int idx = tid + i*128, r = idx >> 3, c = idx & 7;
    *(i32x4*)&outq[(size_t)(t0 + r)*HD + c*16] = *(const i32x4*)&As[r*144 + c*16];
  }
}

// ---------------------------------------------------------------------------
// Kernel 3: MFMA flash attention, operand-swapped, K-split, reg-prefetch.
// (unchanged from round 5 — verified)
// ---------------------------------------------------------------------------
__global__ __launch_bounds__(256)
void attn_mfma_kernel(const int8_t* __restrict__ qq, const float* __restrict__ qsc_in,
                      const int8_t* __restrict__ kq, const float* __restrict__ ksc_in,
                      const int8_t* __restrict__ vq, const float* __restrict__ vsc_in,
                      ushort* __restrict__ aoh, ushort* __restrict__ aol,
                      float* __restrict__ opart0, float* __restrict__ opart1,
                      float* __restrict__ mlm, float* __restrict__ mll) {
  int id = blockIdx.x;
  int h, qb, sp, ktb, kte;
  if (id < 512) {
    sp = id & 1;
    int r = id >> 1;
    h  = r & 15;
    qb = 31 - (r >> 4);
    int nkt = qb + 1, mid = nkt >> 1;
    ktb = sp ? mid : 0;
    kte = sp ? nkt : mid;
  } else {
    int r = id - 512;
    h  = r & 15;
    qb = 15 - (r >> 4);
    sp = -1;
    ktb = 0; kte = qb + 1;
  }
  int hk  = h >> 2;
  int qb0 = qb * 64;
  int nkt_full = qb + 1;

  __shared__ int8_t Ks[64 * 144];
  __shared__ ushort Vt[128 * 72];
  __shared__ float  Pf[4][16 * 68];

  int tid = threadIdx.x;
  int w  = tid >> 6;
  int l  = tid & 63;
  int lg = l & 15;
  int lh = l >> 4;

  const int8_t* qp = &qq[((size_t)h*TT + qb0 + 16*w + lg)*HD + lh*16];
  i32x4 qa0 = *(const i32x4*)qp;
  i32x4 qa1 = *(const i32x4*)(qp + 64);

  int myq = qb0 + 16*w + lg;
  float qsl = qsc_in[(size_t)h*TT + myq] * (SCALE_F * LOG2E);

  float mrun = -1e30f, lrun = 0.f;
  f32x4 acc_o[8];
  #pragma unroll
  for (int dt = 0; dt < 8; ++dt) acc_o[dt] = (f32x4){0.f, 0.f, 0.f, 0.f};

  i32x4 kreg[2];
  int2  vreg[2][2];

#define ISSUE_LOADS(KT)                                                         \
  {                                                                             \
    int kk0 = (KT) * 64;                                                        \
    _Pragma("unroll")                                                           \
    for (int i = 0; i < 2; ++i) {                                               \
      int a = tid + i*256, r = a >> 3, c = a & 7;                               \
      kreg[i] = *(const i32x4*)&kq[((size_t)hk*TT + kk0 + r)*HD + c*16];        \
    }                                                                           \
    _Pragma("unroll")                                                           \
    for (int it = 0; it < 2; ++it) {                                            \
      int a2 = tid + it*256, m2 = a2 & 31, d0 = (a2 >> 5) * 8;                  \
      vreg[it][0] = *(const int2*)&vq[((size_t)hk*TT + kk0 + 2*m2    )*HD + d0];\
      vreg[it][1] = *(const int2*)&vq[((size_t)hk*TT + kk0 + 2*m2 + 1)*HD + d0];\
    }                                                                           \
  }

  ISSUE_LOADS(ktb);

  for (int kt = ktb; kt < kte; ++kt) {
    int k0 = kt * 64;
    __syncthreads();
    #pragma unroll
    for (int i = 0; i < 2; ++i) {
      int a = tid + i*256, r = a >> 3, c = a & 7;
      *(i32x4*)&Ks[r*144 + c*16] = kreg[i];
    }
    #pragma unroll
    for (int it = 0; it < 2; ++it) {
      int a2 = tid + it*256, m2 = a2 & 31, d0 = (a2 >> 5) * 8;
      int xa = vreg[it][0].x, ya = vreg[it][0].y;
      int xb = vreg[it][1].x, yb = vreg[it][1].y;
      #pragma unroll
      for (int j = 0; j < 4; ++j) {
        int v0 = (xa << (24 - 8*j)) >> 24;
        int v1 = (xb << (24 - 8*j)) >> 24;
        uint32_t pk = (fbits((float)v0) >> 16) | ((fbits((float)v1) >> 16) << 16);
        *(uint32_t*)&Vt[(d0 + j)*72 + 2*m2] = pk;
      }
      #pragma unroll
      for (int j = 0; j < 4; ++j) {
        int v0 = (ya << (24 - 8*j)) >> 24;
        int v1 = (yb << (24 - 8*j)) >> 24;
        uint32_t pk = (fbits((float)v0) >> 16) | ((fbits((float)v1) >> 16) << 16);
        *(uint32_t*)&Vt[(d0 + 4 + j)*72 + 2*m2] = pk;
      }
    }
    __syncthreads();
    if (kt + 1 < kte) ISSUE_LOADS(kt + 1);

    i32x4 sacc[4];
    #pragma unroll
    for (int t = 0; t < 4; ++t) sacc[t] = (i32x4){0, 0, 0, 0};
    #pragma unroll
    for (int t = 0; t < 4; ++t) {
      const int8_t* kp = &Ks[(16*t + lg)*144 + lh*16];
      i32x4 b0 = *(const i32x4*)kp;
      i32x4 b1 = *(const i32x4*)(kp + 64);
      sacc[t] = mfma_i8(b0, qa0, sacc[t]);
      sacc[t] = mfma_i8(b1, qa1, sacc[t]);
    }

    f32x4 ksv4[4], vsv4[4];
    #pragma unroll
    for (int t = 0; t < 4; ++t) {
      ksv4[t] = *(const f32x4*)&ksc_in[(size_t)hk*TT + k0 + 16*t + 4*lh];
      vsv4[t] = *(const f32x4*)&vsc_in[(size_t)hk*TT + k0 + 16*t + 4*lh];
    }

    bool maskTile = (kt == nkt_full - 1);
    float sf[4][4];
    #pragma unroll
    for (int t = 0; t < 4; ++t)
      #pragma unroll
      for (int rr = 0; rr < 4; ++rr) {
        float v = (float)sacc[t][rr] * qsl * ksv4[t][rr];
        if (maskTile) {
          int kkg = k0 + 16*t + 4*lh + rr;
          v = (kkg <= myq) ? v : -1e30f;
        }
        sf[t][rr] = v;
      }

    float rm = sf[0][0];
    #pragma unroll
    for (int t = 0; t < 4; ++t)
      #pragma unroll
      for (int rr = 0; rr < 4; ++rr) rm = fmaxf(rm, sf[t][rr]);
    rm = fmaxf(rm, __shfl_xor(rm, 16));
    rm = fmaxf(rm, __shfl_xor(rm, 32));
    float mnew = fmaxf(mrun, rm);
    float corr = EXP2(mrun - mnew);
    mrun = mnew;
    float p[4][4];
    float ps = 0.f;
    #pragma unroll
    for (int t = 0; t < 4; ++t)
      #pragma unroll
      for (int rr = 0; rr < 4; ++rr) { p[t][rr] = EXP2(sf[t][rr] - mnew); ps += p[t][rr]; }
    ps += __shfl_xor(ps, 16);
    ps += __shfl_xor(ps, 32);
    lrun = lrun * corr + ps;

    #pragma unroll
    for (int t = 0; t < 4; ++t) {
      f32x4 pw;
      #pragma unroll
      for (int rr = 0; rr < 4; ++rr) pw[rr] = p[t][rr] * vsv4[t][rr];
      *(f32x4*)&Pf[w][lg*68 + 16*t + 4*lh] = pw;
    }

    #pragma unroll
    for (int dt = 0; dt < 8; ++dt)
      #pragma unroll
      for (int rr = 0; rr < 4; ++rr) acc_o[dt][rr] *= corr;

    s16x8 pahi[2], palo[2];
    #pragma unroll
    for (int kb = 0; kb < 2; ++kb) {
      const float* pr = &Pf[w][lg*68 + kb*32 + lh*8];
      f32x4 x0 = *(const f32x4*)pr;
      f32x4 x1 = *(const f32x4*)(pr + 4);
      float xv[8] = {x0.x, x0.y, x0.z, x0.w, x1.x, x1.y, x1.z, x1.w};
      float lv[8];
      #pragma unroll
      for (int j = 0; j < 8; ++j) {
        uint32_t hb = fbits(xv[j]) & 0xffff0000u;
        union { uint32_t u; float f; } hf; hf.u = hb;
        lv[j] = xv[j] - hf.f;
      }
      union { uint32_t u[4]; s16x8 v; } H, L;
      #pragma unroll
      for (int jj = 0; jj < 4; ++jj) {
        H.u[jj] = (fbits(xv[2*jj]) >> 16) | (fbits(xv[2*jj+1]) & 0xffff0000u);
        L.u[jj] = (fbits(lv[2*jj]) >> 16) | (fbits(lv[2*jj+1]) & 0xffff0000u);
      }
      pahi[kb] = H.v; palo[kb] = L.v;
    }

    #pragma unroll
    for (int dt = 0; dt < 8; ++dt) {
      #pragma unroll
      for (int kb = 0; kb < 2; ++kb) {
        s16x8 vb = *(const s16x8*)&Vt[(16*dt + lg)*72 + kb*32 + lh*8];
        acc_o[dt] = mfma_bf16(vb, pahi[kb], acc_o[dt]);
        acc_o[dt] = mfma_bf16(vb, palo[kb], acc_o[dt]);
      }
    }
  }
#undef ISSUE_LOADS

  if (sp < 0) {
    float invv = 1.0f / lrun;
    size_t base = (size_t)myq*DD + (size_t)h*HD;
    #pragma unroll
    for (int dt = 0; dt < 8; ++dt) {
      ushort4 Hv, Lv;
      float v0 = acc_o[dt][0]*invv, v1 = acc_o[dt][1]*invv;
      float v2 = acc_o[dt][2]*invv, v3 = acc_o[dt][3]*invv;
      Hv.x = bf16_rne(v0); Hv.y = bf16_rne(v1); Hv.z = bf16_rne(v2); Hv.w = bf16_rne(v3);
      Lv.x = bf16_rne(v0 - bf16_to_f(Hv.x)); Lv.y = bf16_rne(v1 - bf16_to_f(Hv.y));
      Lv.z = bf16_rne(v2 - bf16_to_f(Hv.z)); Lv.w = bf16_rne(v3 - bf16_to_f(Hv.w));
      *(ushort4*)&aoh[base + 16*dt + 4*lh] = Hv;
      *(ushort4*)&aol[base + 16*dt + 4*lh] = Lv;
    }
  } else {
    int tile = h*16 + (qb - 16);
    float* op = (sp == 0 ? opart0 : opart1) + (size_t)tile*8192 + (size_t)(16*w + lg)*128;
    #pragma unroll
    for (int dt = 0; dt < 8; ++dt)
      *(f32x4*)&op[16*dt + 4*lh] = acc_o[dt];
    if (lh == 0) {
      mlm[sp*16384 + tile*64 + 16*w + lg] = mrun;
      mll[sp*16384 + tile*64 + 16*w + lg] = lrun;
    }
  }
}

// ---------------------------------------------------------------------------
// Kernel 3b: merge the two K-split halves for qb >= 16.
// ---------------------------------------------------------------------------
__global__ __launch_bounds__(256)
void merge_kernel(const float* __restrict__ opart0, const float* __restrict__ opart1,
                  const float* __restrict__ mlm, const float* __restrict__ mll,
                  ushort* __restrict__ aoh, ushort* __restrict__ aol) {
  int tile = blockIdx.x;
  int h = tile >> 4, j = tile & 15;
  int tid = threadIdx.x;
  int row = tid >> 2;
  int cseg = (tid & 3) * 32;
  float m1 = mlm[tile*64 + row], m2 = mlm[16384 + tile*64 + row];
  float l1 = mll[tile*64 + row], l2 = mll[16384 + tile*64 + row];
  float m = fmaxf(m1, m2);
  float c1 = EXP2(m1 - m), c2 = EXP2(m2 - m);
  float inv = 1.0f / (l1*c1 + l2*c2);
  const float* p0 = opart0 + (size_t)tile*8192 + row*128 + cseg;
  const float* p1 = opart1 + (size_t)tile*8192 + row*128 + cseg;
  size_t ob = (size_t)(1024 + j*64 + row)*DD + (size_t)h*HD + cseg;
  #pragma unroll
  for (int c4 = 0; c4 < 8; ++c4) {
    f32x4 a = *(const f32x4*)&p0[c4*4];
    f32x4 b = *(const f32x4*)&p1[c4*4];
    ushort4 Hv, Lv;
    #pragma unroll
    for (int e = 0; e < 4; ++e) {
      float v = (a[e]*c1 + b[e]*c2) * inv;
      ushort hb = bf16_rne(v);
      ushort lb = bf16_rne(v - bf16_to_f(hb));
      ((ushort*)&Hv)[e] = hb;
      ((ushort*)&Lv)[e] = lb;
    }
    *(ushort4*)&aoh[ob + c4*4] = Hv;
    *(ushort4*)&aol[ob + c4*4] = Lv;
  }
}

// ---------------------------------------------------------------------------
// Kernel 3c: split wo (f32) into hi/lo bf16.
// ---------------------------------------------------------------------------
__global__ __launch_bounds__(256)
void wcvt_kernel(const float* __restrict__ wom, ushort* __restrict__ woh,
                 ushort* __restrict__ wol) {
  size_t base = ((size_t)blockIdx.x * 256 + threadIdx.x) * 8;
  float4 a = *(const float4*)&wom[base];
  float4 b = *(const float4*)&wom[base + 4];
  float vv[8] = {a.x, a.y, a.z, a.w, b.x, b.y, b.z, b.w};
  s16x8 H, L;
  #pragma unroll
  for (int j = 0; j < 8; ++j) {
    ushort hb = bf16_rne(vv[j]);
    float lo = vv[j] - bf16_to_f(hb);
    H[j] = (short)hb;
    L[j] = (short)bf16_rne(lo);
  }
  *(s16x8*)&woh[base] = H;
  *(s16x8*)&wol[base] = L;
}

// ---------------------------------------------------------------------------
// Kernel 4: wo GEMM on bf16 MFMA with 3-product split (unchanged, verified).
// ---------------------------------------------------------------------------
__global__ __launch_bounds__(256)
void wo_gemm_kernel(const ushort* __restrict__ aoh, const ushort* __restrict__ aol,
                    const ushort* __restrict__ woh, const ushort* __restrict__ wol,
                    float* __restrict__ outp) {
  int o0 = blockIdx.x * 128;
  int t0 = blockIdx.y * 128;
  __shared__ ushort AH[128 * 72];
  __shared__ ushort AL[128 * 72];
  __shared__ ushort BH[128 * 72];
  __shared__ ushort BL[128 * 72];
  int tid = threadIdx.x;
  int wv4 = tid >> 6;
  int wr = wv4 >> 1, wc = wv4 & 1;
  int l  = tid & 63;
  int lg = l & 15;
  int lh = l >> 4;

  f32x4 acc[4][4];
  #pragma unroll
  for (int ti = 0; ti < 4; ++ti)
    #pragma unroll
    for (int tj = 0; tj < 4; ++tj) acc[ti][tj] = (f32x4){0.f,0.f,0.f,0.f};

  for (int kt = 0; kt < DD/64; ++kt) {
    int k0 = kt * 64;
    __syncthreads();
    #pragma unroll
    for (int i = 0; i < 4; ++i) {
      int idx = tid + i*256, r = idx >> 3, c = idx & 7;
      size_t ga = (size_t)(t0 + r)*DD + k0 + c*8;
      size_t gb = (size_t)(o0 + r)*DD + k0 + c*8;
      *(s16x8*)&AH[r*72 + c*8] = *(const s16x8*)&aoh[ga];
      *(s16x8*)&AL[r*72 + c*8] = *(const s16x8*)&aol[ga];
      *(s16x8*)&BH[r*72 + c*8] = *(const s16x8*)&woh[gb];
      *(s16x8*)&BL[r*72 + c*8] = *(const s16x8*)&wol[gb];
    }
    __syncthreads();
    #pragma unroll
    for (int s = 0; s < 2; ++s) {
      s16x8 ah[4], al[4];
      #pragma unroll
      for (int ti = 0; ti < 4; ++ti) {
        int ab = (wr*64 + ti*16 + lg)*72 + s*32 + lh*8;
        ah[ti] = *(const s16x8*)&AH[ab];
        al[ti] = *(const s16x8*)&AL[ab];
      }
      #pragma unroll
      for (int tj = 0; tj < 4; ++tj) {
        int bb = (wc*64 + tj*16 + lg)*72 + s*32 + lh*8;
        s16x8 bh = *(const s16x8*)&BH[bb];
        s16x8 bl = *(const s16x8*)&BL[bb];
        #pragma unroll
        for (int ti = 0; ti < 4; ++ti) {
          acc[ti][tj] = mfma_bf16(ah[ti], bh, acc[ti][tj]);
          acc[ti][tj] = mfma_bf16(ah[ti], bl, acc[ti][tj]);
          acc[ti][tj] = mfma_bf16(al[ti], bh, acc[ti][tj]);
        }
      }
    }
  }

  #pragma unroll
  for (int ti = 0; ti < 4; ++ti)
    #pragma unroll
    for (int tj = 0; tj < 4; ++tj)
      #pragma unroll
      for (int rr = 0; rr < 4; ++rr) {
        int t = t0 + wr*64 + ti*16 + lh*4 + rr;
        int o = o0 + wc*64 + tj*16 + lg;
        outp[(size_t)t*DD + o] = acc[ti][tj][rr];
      }
}

// ---------------------------------------------------------------------------
extern "C" void kernel_launch(void* const* d_in, const int* in_sizes, int n_in,
                              void* d_out, int out_size, void* d_ws, size_t ws_size,
                              hipStream_t stream) {
  (void)in_sizes; (void)n_in; (void)out_size; (void)ws_size;
  const float* x  = (const float*)d_in[0];
  const float* wq = (const float*)d_in[1];
  const float* wk = (const float*)d_in[2];
  const float* wv = (const float*)d_in[3];
  const float* wo = (const float*)d_in[4];
  float* out = (float*)d_out;

  char* ws = (char*)d_ws;
  const size_t MB = 1048576;
  int8_t* qx  = (int8_t*)(ws);           // [2048][2048]; dead after proj
  int8_t* qwq = (int8_t*)(ws + 4*MB);    // dead after proj
  int8_t* qwk = (int8_t*)(ws + 8*MB);    // dead after proj
  int8_t* qwv = (int8_t*)(ws + 9*MB);    // dead after proj
  int8_t* qqp = (int8_t*)(ws + 10*MB);   // [16][2048][128]; dead after attn
  int8_t* kqp = (int8_t*)(ws + 14*MB);   // [4][2048][128];  dead after attn
  int8_t* vqp = (int8_t*)(ws + 15*MB);   // [4][2048][128];  dead after attn
  float* xs  = (float*)(ws + 16*MB);
  float* wqs = xs + 2048;
  float* wks = wqs + 2048;
  float* wvs = wks + 512;
  float* qsc = wvs + 512;
  float* ksc = qsc + (size_t)NH*TT;
  float* vsc = ksc + (size_t)NKV*TT;
  ushort* aoh = (ushort*)(ws + 16*MB + 262144);   // 8 MB
  ushort* aol = (ushort*)(ws + 24*MB + 262144);   // 8 MB (ends 32.25 MB)
  // RoPE table: 1 MB over the aoh region — read by proj, overwritten later
  // by attn (attn runs after proj; no overlap in liveness).
  float2* ropet = (float2*)(ws + 16*MB + 262144);
  // attn-phase scratch over dead regions:
  float* opart0 = (float*)(ws);                   // 8 MiB (over qx/qwq, dead)
  float* mlm    = (float*)(ws + 8*MB);            // 128 KB (over qwk, dead)
  float* mll    = (float*)(ws + 8*MB + 131072);   // 128 KB
  float* opart1 = out;                            // 8 MiB scratch in d_out
  // wo-phase scratch (after merge, everything below 16 MB is dead):
  ushort* woh = (ushort*)(ws);                    // 8 MB
  ushort* wol = (ushort*)(ws + 8*MB);             // 8 MB

  rope_table_kernel<<<512, 256, 0, stream>>>(ropet);
  quant_rows_kernel<<<5120, 256, 0, stream>>>(x, wq, wk, wv,
                                              qx, xs, qwq, wqs, qwk, wks, qwv, wvs);
  proj_kernel<<<768, 128, 0, stream>>>(
      qx, xs, qwq, wqs, qwk, wks, qwv, wvs, ropet,
      qqp, qsc, kqp, ksc, vqp, vsc);
  attn_mfma_kernel<<<768, 256, 0, stream>>>(
      qqp, qsc, kqp, ksc, vqp, vsc, aoh, aol, opart0, opart1, mlm, mll);
  merge_kernel<<<256, 256, 0, stream>>>(opart0, opart1, mlm, mll, aoh, aol);
  wcvt_kernel<<<2048, 256, 0, stream>>>(wo, woh, wol);
  wo_gemm_kernel<<<dim3(DD/128, TT/128), 256, 0, stream>>>(aoh, aol, woh, wol, out);
}